// Round 1
// baseline (121.082 us; speedup 1.0000x reference)
//
#include <hip/hip_runtime.h>
#include <math.h>

// Depthwise 5x5 Gaussian blur, sigma from device scalar.
// x: (16, 256, 64, 64) fp32, out same, zero pad 2. Separable.
//
// R4: LDS-free, fully register-resident. One block = one plane.
// Each thread owns a 4x4 output tile (rows r0..r0+3, cols 4*c4..4*c4+3).
// It loads the 8 input rows r0-2..r0+5 it needs: an aligned float4 (its own
// 4 cols) plus float2 left/right halos = exactly the 8 floats per row the
// horizontal pass consumes. Neighboring lanes/threads overlap heavily in
// these reads, but L1/L2 absorb the overlap -> HBM traffic stays ~1x.
// Zero padding implemented by clamped addresses + multiplicative masks
// (keeps loads unconditional so the compiler can hoist/pipeline all 24).
// No LDS, no __syncthreads: waves are fully independent.

constexpr int Hh   = 64;
constexpr int Ww   = 64;
constexpr int KS   = 5;
constexpr int PADc = 2;

__global__ __launch_bounds__(256, 4) void gauss5(const float* __restrict__ x,
                                                 const float* __restrict__ sigma,
                                                 float* __restrict__ out) {
    const int t  = threadIdx.x;
    const int c4 = t & 15;          // float4-column 0..15
    const int r0 = (t >> 4) << 2;   // output rows r0..r0+3

    // --- normalized 1-D Gaussian taps (outer product sums to 1, matching ref) ---
    const float sg = sigma[0];
    const float c2 = -1.0f / (2.0f * sg * sg);
    float g[KS];
    float gsum = 0.0f;
#pragma unroll
    for (int i = 0; i < KS; ++i) {
        float d = (float)(i - PADc);
        g[i] = expf(d * d * c2);
        gsum += g[i];
    }
    const float ginv = 1.0f / gsum;
#pragma unroll
    for (int i = 0; i < KS; ++i) g[i] *= ginv;

    const size_t plane = blockIdx.x;
    const float* __restrict__ xp = x   + plane * (size_t)(Hh * Ww);
    float* __restrict__ op       = out + plane * (size_t)(Hh * Ww);

    // column-halo setup: left float2 covers cols 4*c4-2..4*c4-1,
    // right float2 covers cols 4*c4+4..4*c4+5; clamped+masked at edges.
    const int   loff  = (c4 > 0)  ? (4 * c4 - 2) : 0;   // 8B-aligned
    const int   roff  = (c4 < 15) ? (4 * c4 + 4) : 0;   // 16B-aligned
    const float lmask = (c4 > 0)  ? 1.0f : 0.0f;
    const float rmask = (c4 < 15) ? 1.0f : 0.0f;

    // --- horizontal pass for the 8 rows this thread's vertical window needs ---
    float4 h[8];
#pragma unroll
    for (int i = 0; i < 8; ++i) {
        const int   rr = r0 - 2 + i;
        const int   rc = rr < 0 ? 0 : (rr > Hh - 1 ? Hh - 1 : rr);
        const float rm = (rr >= 0 && rr < Hh) ? 1.0f : 0.0f;
        const float* row = xp + rc * Ww;

        float4 mv = *(const float4*)(row + 4 * c4);
        float2 lv = *(const float2*)(row + loff);
        float2 rv = *(const float2*)(row + roff);

        const float lm  = rm * lmask;
        const float rm2 = rm * rmask;
        const float l0 = lv.x * lm,  l1 = lv.y * lm;
        const float rA = rv.x * rm2, rB = rv.y * rm2;
        const float m0 = mv.x * rm,  m1 = mv.y * rm;
        const float m2 = mv.z * rm,  m3 = mv.w * rm;

        h[i].x = g[0]*l0 + g[1]*l1 + g[2]*m0 + g[3]*m1 + g[4]*m2;
        h[i].y = g[0]*l1 + g[1]*m0 + g[2]*m1 + g[3]*m2 + g[4]*m3;
        h[i].z = g[0]*m0 + g[1]*m1 + g[2]*m2 + g[3]*m3 + g[4]*rA;
        h[i].w = g[0]*m1 + g[1]*m2 + g[2]*m3 + g[3]*rA + g[4]*rB;
    }

    // --- vertical pass + store ---
#pragma unroll
    for (int i = 0; i < 4; ++i) {
        float4 acc;
        acc.x = g[0] * h[i].x;
        acc.y = g[0] * h[i].y;
        acc.z = g[0] * h[i].z;
        acc.w = g[0] * h[i].w;
#pragma unroll
        for (int j = 1; j < KS; ++j) {
            acc.x += g[j] * h[i + j].x;
            acc.y += g[j] * h[i + j].y;
            acc.z += g[j] * h[i + j].z;
            acc.w += g[j] * h[i + j].w;
        }
        *(float4*)(op + (r0 + i) * Ww + 4 * c4) = acc;
    }
}

extern "C" void kernel_launch(void* const* d_in, const int* in_sizes, int n_in,
                              void* d_out, int out_size, void* d_ws, size_t ws_size,
                              hipStream_t stream) {
    const float* x     = (const float*)d_in[0];
    const float* sigma = (const float*)d_in[1];
    float* out         = (float*)d_out;
    const int planes = in_sizes[0] / (Hh * Ww);  // 4096
    gauss5<<<planes, 256, 0, stream>>>(x, sigma, out);
}

// Round 3
// 107.282 us; speedup vs baseline: 1.1286x; 1.1286x over previous
//
#include <hip/hip_runtime.h>
#include <math.h>

// Depthwise 5x5 Gaussian blur, sigma from device scalar.
// x: (16, 256, 64, 64) fp32, out same, zero pad 2. Separable.
//
// R6 = R5 with the nontemporal-store compile fix (native clang vector type).
//  - One block = one plane (grid 4096). LDS = exact unpadded 64x64 plane
//    (16 KB) -> 8 blocks/CU resident (wave cap), 2x the occupancy of the
//    39 KB double-buffered R3. Inter-block overlap hides staging latency,
//    so no prefetch/double-buffer machinery is needed.
//  - Staging via __builtin_amdgcn_global_load_lds width=16: the unpadded
//    linear layout satisfies its wave-uniform-base + lane*16 requirement
//    (the padded R3 layout could not). No VGPR round trip, no ds_write.
//  - Zero padding handled on the LDS *reads* with clamped addresses +
//    multiplicative masks (cheap VALU), instead of zero-filled halo rows.
//  - Each thread: 4x4 output tile. 8 rows of horizontal pass from LDS
//    (float4 mid + float2 halos), vertical pass in registers, 16B
//    nontemporal store (output has zero reuse).

constexpr int Hh   = 64;
constexpr int Ww   = 64;
constexpr int KS   = 5;
constexpr int PADc = 2;

typedef const __attribute__((address_space(1))) unsigned int  glb_u32;
typedef __attribute__((address_space(3))) unsigned int        lds_u32;
typedef float f32x4 __attribute__((ext_vector_type(4)));

__global__ __launch_bounds__(256, 8) void gauss5(const float* __restrict__ x,
                                                 const float* __restrict__ sigma,
                                                 float* __restrict__ out) {
    __shared__ alignas(16) float sIn[Hh * Ww];   // 16,384 B — exact plane copy

    const int t  = threadIdx.x;
    const int c4 = t & 15;          // float4-column 0..15
    const int r0 = (t >> 4) << 2;   // output rows r0..r0+3

    const size_t plane = blockIdx.x;
    const float* __restrict__ xp = x   + plane * (size_t)(Hh * Ww);
    float* __restrict__ op       = out + plane * (size_t)(Hh * Ww);

    // --- stage plane -> LDS directly (4 x 16B per thread, linear) ---
#pragma unroll
    for (int k = 0; k < 4; ++k) {
        const int idx = (t + k * 256) * 4;     // float index, 16B-granular
        __builtin_amdgcn_global_load_lds((glb_u32*)(xp + idx),
                                         (lds_u32*)(&sIn[idx]), 16, 0, 0);
    }

    // --- normalized 1-D Gaussian taps (overlaps the staging loads) ---
    const float sg = sigma[0];
    const float c2 = -1.0f / (2.0f * sg * sg);
    float g[KS];
    float gsum = 0.0f;
#pragma unroll
    for (int i = 0; i < KS; ++i) {
        float d = (float)(i - PADc);
        g[i] = expf(d * d * c2);
        gsum += g[i];
    }
    const float ginv = 1.0f / gsum;
#pragma unroll
    for (int i = 0; i < KS; ++i) g[i] *= ginv;

    // column-halo setup: left float2 covers cols 4*c4-2..4*c4-1,
    // right float2 covers cols 4*c4+4..4*c4+5; clamped+masked at edges.
    const int   loff  = (c4 > 0)  ? (4 * c4 - 2) : 0;   // 8B-aligned
    const int   roff  = (c4 < 15) ? (4 * c4 + 4) : 0;   // 16B-aligned
    const float lmask = (c4 > 0)  ? 1.0f : 0.0f;
    const float rmask = (c4 < 15) ? 1.0f : 0.0f;

    __syncthreads();   // drains vmcnt(0) -> staged plane visible

    // --- horizontal pass for the 8 rows this thread's window needs ---
    float4 h[8];
#pragma unroll
    for (int i = 0; i < 8; ++i) {
        const int   rr = r0 - 2 + i;
        const int   rc = rr < 0 ? 0 : (rr > Hh - 1 ? Hh - 1 : rr);
        const float rm = (rr >= 0 && rr < Hh) ? 1.0f : 0.0f;
        const float* row = &sIn[rc * Ww];

        float4 mv = *(const float4*)(row + 4 * c4);
        float2 lv = *(const float2*)(row + loff);
        float2 rv = *(const float2*)(row + roff);

        const float lm  = rm * lmask;
        const float rmk = rm * rmask;
        const float l0 = lv.x * lm,  l1 = lv.y * lm;
        const float rA = rv.x * rmk, rB = rv.y * rmk;
        const float m0 = mv.x * rm,  m1 = mv.y * rm;
        const float m2 = mv.z * rm,  m3 = mv.w * rm;

        h[i].x = g[0]*l0 + g[1]*l1 + g[2]*m0 + g[3]*m1 + g[4]*m2;
        h[i].y = g[0]*l1 + g[1]*m0 + g[2]*m1 + g[3]*m2 + g[4]*m3;
        h[i].z = g[0]*m0 + g[1]*m1 + g[2]*m2 + g[3]*m3 + g[4]*rA;
        h[i].w = g[0]*m1 + g[1]*m2 + g[2]*m3 + g[3]*rA + g[4]*rB;
    }

    // --- vertical pass + nontemporal store (output has no reuse) ---
#pragma unroll
    for (int i = 0; i < 4; ++i) {
        f32x4 acc;
        acc.x = g[0] * h[i].x;
        acc.y = g[0] * h[i].y;
        acc.z = g[0] * h[i].z;
        acc.w = g[0] * h[i].w;
#pragma unroll
        for (int j = 1; j < KS; ++j) {
            acc.x += g[j] * h[i + j].x;
            acc.y += g[j] * h[i + j].y;
            acc.z += g[j] * h[i + j].z;
            acc.w += g[j] * h[i + j].w;
        }
        __builtin_nontemporal_store(acc, (f32x4*)(op + (r0 + i) * Ww + 4 * c4));
    }
}

extern "C" void kernel_launch(void* const* d_in, const int* in_sizes, int n_in,
                              void* d_out, int out_size, void* d_ws, size_t ws_size,
                              hipStream_t stream) {
    const float* x     = (const float*)d_in[0];
    const float* sigma = (const float*)d_in[1];
    float* out         = (float*)d_out;
    const int planes = in_sizes[0] / (Hh * Ww);  // 4096
    gauss5<<<planes, 256, 0, stream>>>(x, sigma, out);
}